// Round 4
// baseline (172.392 us; speedup 1.0000x reference)
//
#include <hip/hip_runtime.h>

constexpr int NB   = 2;
constexpr int CIN  = 128;
constexpr int TT   = 8;
constexpr int HH   = 56;
constexpr int WW   = 56;
constexpr int S    = TT * HH * WW;      // 25088
constexpr int DK   = 16;
constexpr int DV   = 128;
constexpr int TAPS = 147;               // 3*7*7
constexpr int NOUT = DK + DV;           // 144
// padded channel-last v: [b][t:10][h:62][w:62][c:128]
constexpr int VPT = 10, VPH = 62, VPW = 62;
constexpr int PCELLS = NB * VPT * VPH * VPW;   // 76880 padded cells
constexpr int WSTR = 149;               // weff LDS stride (odd*... 21 mod 32 odd -> conflict-free)
constexpr float EPSf = 1e-6f;

// ---------------------------------------------------------------------------
// Wp[o][c] -> Wpt[c][144]
// ---------------------------------------------------------------------------
__global__ __launch_bounds__(256) void k_twp(
    const float* __restrict__ Wp, float* __restrict__ Wpt)
{
    int i = blockIdx.x * 256 + threadIdx.x;
    if (i >= CIN * NOUT) return;
    int c = i / NOUT, o = i - c * NOUT;
    Wpt[i] = Wp[o * CIN + c];
}

// ---------------------------------------------------------------------------
// Zero only the halo of vcl (13.7 MB instead of 39.4 MB memset).
// 32 threads per padded cell (128 ch / float4); interior threads exit.
// ---------------------------------------------------------------------------
__global__ __launch_bounds__(256) void k_zero(float* __restrict__ vcl)
{
    int gid  = blockIdx.x * 256 + threadIdx.x;
    int cell = gid >> 5;
    int ch4  = gid & 31;
    if (cell >= PCELLS) return;
    int rb = cell;
    int wp = rb % VPW; rb /= VPW;
    int hp = rb % VPH; rb /= VPH;
    int tp = rb % VPT;
    if (tp >= 1 && tp <= 8 && hp >= 3 && hp <= 58 && wp >= 3 && wp <= 58) return;
    float4 z = {0.f, 0.f, 0.f, 0.f};
    *reinterpret_cast<float4*>(vcl + (size_t)cell * 128 + ch4 * 4) = z;
}

// ---------------------------------------------------------------------------
// k_proj: block = 4 waves; each wave = same 64 positions, one 36-channel
// quarter. x loads software-pipelined 4 deep (hide L3 latency).
// v scaled in-register, written once (channel-last padded layout).
// ---------------------------------------------------------------------------
__global__ __launch_bounds__(256) void k_proj(
    const float* __restrict__ x, const float* __restrict__ Wpt,
    float* __restrict__ qn, float* __restrict__ vcl)
{
    __shared__ float svl[4 * 64];
    int tid = threadIdx.x;
    int pos = tid & 63;
    int og  = __builtin_amdgcn_readfirstlane(tid >> 6);
    int gid = blockIdx.x * 64 + pos;                     // < NB*S
    int b = gid / S, p = gid - b * S;

    const float* xp = x + (size_t)b * CIN * S + p;
    const float* wr = Wpt + og * 36;

    float acc[36];
#pragma unroll
    for (int o = 0; o < 36; ++o) acc[o] = 0.f;

    float xc[4], xn[4];
#pragma unroll
    for (int u = 0; u < 4; ++u) xc[u] = xp[(size_t)u * S];

#pragma unroll 1
    for (int c0 = 0; c0 < CIN; c0 += 4) {
        if (c0 + 4 < CIN) {
#pragma unroll
            for (int u = 0; u < 4; ++u) xn[u] = xp[(size_t)(c0 + 4 + u) * S];
        }
#pragma unroll
        for (int u = 0; u < 4; ++u) {
            const float* wc = wr + (size_t)(c0 + u) * NOUT;
#pragma unroll
            for (int o = 0; o < 36; ++o)
                acc[o] = fmaf(xc[u], wc[o], acc[o]);
        }
#pragma unroll
        for (int u = 0; u < 4; ++u) xc[u] = xn[u];
    }

    float s_all = 0.f;
#pragma unroll
    for (int o = 0; o < 36; ++o) s_all += acc[o] * acc[o];
    float ssq = 0.f;
    if (og == 0) {
#pragma unroll
        for (int o = 0; o < 16; ++o) ssq += acc[o] * acc[o];
    }
    svl[og * 64 + pos] = s_all - ssq;   // v-part of this quarter
    __syncthreads();
    float ssv = svl[pos] + svl[64 + pos] + svl[128 + pos] + svl[192 + pos];
    float vsc = 1.0f / sqrtf(ssv + EPSf);

    if (og == 0) {
        float qsc = 1.0f / sqrtf(ssq + EPSf);
#pragma unroll
        for (int o = 0; o < DK; ++o)
            qn[((size_t)b * DK + o) * S + p] = acc[o] * qsc;
    }

    int t  = p / (HH * WW);
    int hw = p - t * (HH * WW);
    int h  = hw / WW;
    int w  = hw - h * WW;
    float* vd = vcl + (((size_t)(b * VPT + t + 1) * VPH + (h + 3)) * VPW + (w + 3)) * 128;

    if (og == 0) {
#pragma unroll
        for (int j = 0; j < 20; j += 4) {
            float4 v4 = {acc[16 + j] * vsc, acc[17 + j] * vsc,
                         acc[18 + j] * vsc, acc[19 + j] * vsc};
            *reinterpret_cast<float4*>(vd + j) = v4;
        }
    } else {
        vd += og * 36 - 16;
#pragma unroll
        for (int j = 0; j < 36; j += 4) {
            float4 v4 = {acc[j] * vsc, acc[j + 1] * vsc,
                         acc[j + 2] * vsc, acc[j + 3] * vsc};
            *reinterpret_cast<float4*>(vd + j) = v4;
        }
    }
}

// ---------------------------------------------------------------------------
// k_out: block = (b,t,h) row, 256 threads = 4 waves.
//   Phase 1: q row -> LDS.
//   Phase 2: weff[w][tap] into LDS (stride 149 -> conflict-free writes).
//   Phase 3: thread = (cc: 4 channels, wt: 7 outputs). One float4 v load
//            per window step feeds ~17 FMAs; weff broadcast from LDS.
// ---------------------------------------------------------------------------
__global__ __launch_bounds__(256) void k_out(
    const float* __restrict__ vcl, const float* __restrict__ qn,
    const float* __restrict__ wh2, float* __restrict__ out)
{
    __shared__ float q_s[DK * WW];       // 3.5 KB
    __shared__ float weff[WW * WSTR];    // 33.4 KB

    int tid = threadIdx.x;
    // XCD-chunked swizzle: 896 = 8 * 112
    int bid = blockIdx.x;
    int nid = (bid & 7) * 112 + (bid >> 3);
    int b   = nid / 448;
    int rem = nid - b * 448;
    int t   = rem / 56, h = rem - t * 56;
    int pbase = t * (HH * WW) + h * WW;

    for (int i = tid; i < DK * WW; i += 256) {
        int k = i / 56, w = i - k * 56;
        q_s[i] = qn[((size_t)b * DK + k) * S + pbase + w];
    }
    __syncthreads();

    if (tid < 224) {
        int w = tid % 56, q4 = tid / 56;
        float qr[DK];
#pragma unroll
        for (int k = 0; k < DK; ++k) qr[k] = q_s[k * 56 + w];
#pragma unroll 1
        for (int tap = q4; tap < TAPS; tap += 4) {
            float a = 0.f;
#pragma unroll
            for (int k = 0; k < DK; ++k)
                a = fmaf(qr[k], wh2[k * TAPS + tap], a);
            weff[w * WSTR + tap] = a;
        }
    }
    __syncthreads();

    int cc = tid & 31;       // 32 chunks x 4 channels = 128
    int wt = tid >> 5;       // 8 tiles x 7 outputs    = 56
    int wbase = wt * 7;

    const float* vbase = vcl
        + ((size_t)(b * VPT + t) * VPH + h) * VPW * 128
        + (size_t)wbase * 128 + cc * 4;

    float acc[7][4];
#pragma unroll
    for (int k = 0; k < 7; ++k)
#pragma unroll
        for (int j = 0; j < 4; ++j) acc[k][j] = 0.f;

#pragma unroll 1
    for (int dz = 0; dz < 3; ++dz) {
#pragma unroll 1
        for (int dy = 0; dy < 7; ++dy) {
            const float* vr = vbase + (size_t)((dz * VPH + dy) * VPW) * 128;
            const float* wrow = &weff[wbase * WSTR + (dz * 7 + dy) * 7];
#pragma unroll
            for (int j = 0; j < 13; ++j) {
                float4 A = *reinterpret_cast<const float4*>(vr + j * 128);
                int k0 = (j - 6 > 0) ? (j - 6) : 0;
                int k1 = (j < 6) ? j : 6;
#pragma unroll
                for (int k = 0; k < 7; ++k) {
                    if (k < k0 || k > k1) continue;      // compile-time pruned
                    float wv = wrow[k * WSTR + (j - k)];
                    acc[k][0] = fmaf(wv, A.x, acc[k][0]);
                    acc[k][1] = fmaf(wv, A.y, acc[k][1]);
                    acc[k][2] = fmaf(wv, A.z, acc[k][2]);
                    acc[k][3] = fmaf(wv, A.w, acc[k][3]);
                }
            }
        }
    }

    size_t ob = ((size_t)b * DV + cc * 4) * S + pbase + wbase;
#pragma unroll
    for (int j = 0; j < 4; ++j)
#pragma unroll
        for (int k = 0; k < 7; ++k)
            out[ob + (size_t)j * S + k] = acc[k][j];
}

// ---------------------------------------------------------------------------
extern "C" void kernel_launch(void* const* d_in, const int* in_sizes, int n_in,
                              void* d_out, int out_size, void* d_ws, size_t ws_size,
                              hipStream_t stream)
{
    const float* x   = (const float*)d_in[0];   // (2,128,8,56,56)
    const float* Wp  = (const float*)d_in[1];   // (144,128)
    const float* wh2 = (const float*)d_in[2];   // (16,1,3,7,7) -> [k][147]
    float* out = (float*)d_out;                 // (2,128,8,56,56)

    float* ws  = (float*)d_ws;
    float* Wpt = ws;                                   //      18,432 floats
    float* qn  = Wpt + (size_t)CIN * NOUT;             //     802,816 floats
    float* vcl = qn  + (size_t)NB * DK * S;            //   9,840,640 floats

    k_twp <<<dim3((CIN * NOUT + 255) / 256), dim3(256), 0, stream>>>(Wp, Wpt);
    k_zero<<<dim3((PCELLS * 32 + 255) / 256), dim3(256), 0, stream>>>(vcl);
    k_proj<<<dim3(NB * S / 64), dim3(256), 0, stream>>>(x, Wpt, qn, vcl);
    k_out <<<dim3(NB * TT * HH), dim3(256), 0, stream>>>(vcl, qn, wh2, out);
}

// Round 5
// 139.015 us; speedup vs baseline: 1.2401x; 1.2401x over previous
//
#include <hip/hip_runtime.h>

constexpr int NB   = 2;
constexpr int CIN  = 128;
constexpr int TT   = 8;
constexpr int HH   = 56;
constexpr int WW   = 56;
constexpr int S    = TT * HH * WW;      // 25088
constexpr int DK   = 16;
constexpr int DV   = 128;
constexpr int TAPS = 147;               // 3*7*7
constexpr int NOUT = DK + DV;           // 144
// padded channel-last v: [b][t:10][h:62][w:62][c:128]
constexpr int VPT = 10, VPH = 62, VPW = 62;
constexpr int PCELLS = NB * VPT * VPH * VPW;   // 76880 padded cells
constexpr int WSTR = 149;               // weff LDS stride (21 mod 32, odd -> conflict-free)
constexpr float EPSf = 1e-6f;

// ---------------------------------------------------------------------------
// Wp[o][c] -> Wpt[c][144]
// ---------------------------------------------------------------------------
__global__ __launch_bounds__(256) void k_twp(
    const float* __restrict__ Wp, float* __restrict__ Wpt)
{
    int i = blockIdx.x * 256 + threadIdx.x;
    if (i >= CIN * NOUT) return;
    int c = i / NOUT, o = i - c * NOUT;
    Wpt[i] = Wp[o * CIN + c];
}

// ---------------------------------------------------------------------------
// Zero only the halo of vcl (13.7 MB instead of 39.4 MB memset).
// ---------------------------------------------------------------------------
__global__ __launch_bounds__(256) void k_zero(float* __restrict__ vcl)
{
    int gid  = blockIdx.x * 256 + threadIdx.x;
    int cell = gid >> 5;
    int ch4  = gid & 31;
    if (cell >= PCELLS) return;
    int rb = cell;
    int wp = rb % VPW; rb /= VPW;
    int hp = rb % VPH; rb /= VPH;
    int tp = rb % VPT;
    if (tp >= 1 && tp <= 8 && hp >= 3 && hp <= 58 && wp >= 3 && wp <= 58) return;
    float4 z = {0.f, 0.f, 0.f, 0.f};
    *reinterpret_cast<float4*>(vcl + (size_t)cell * 128 + ch4 * 4) = z;
}

// ---------------------------------------------------------------------------
// k_proj: block = 576 threads = 9 waves, all sharing one 64-position x tile
// (L1 reuse). Wave og=0 computes q[16]; waves og=1..8 compute 16 v-channels
// each. acc[16] per wave -> no spill under any VGPR cap. Weights are one
// contiguous s_load_dwordx16 per c. ssv reduced across v-waves in LDS.
// ---------------------------------------------------------------------------
__global__ __launch_bounds__(576) void k_proj(
    const float* __restrict__ x, const float* __restrict__ Wpt,
    float* __restrict__ qn, float* __restrict__ vcl)
{
    __shared__ float svl[9 * 64];
    int tid = threadIdx.x;
    int pos = tid & 63;
    int og  = __builtin_amdgcn_readfirstlane(tid >> 6);   // 0..8, wave-uniform
    int gid = blockIdx.x * 64 + pos;                      // < NB*S (784*64)
    int b = gid / S, p = gid - b * S;

    const float* xp = x + (size_t)b * CIN * S + p;
    const float* wr = Wpt + og * 16;        // Wpt[c][144]; our 16 contiguous outs

    float acc[16];
#pragma unroll
    for (int o = 0; o < 16; ++o) acc[o] = 0.f;

#pragma unroll 4
    for (int c = 0; c < CIN; ++c) {
        float xc = xp[(size_t)c * S];
        const float* wc = wr + c * NOUT;
#pragma unroll
        for (int o = 0; o < 16; ++o)
            acc[o] = fmaf(xc, wc[o], acc[o]);
    }

    float ss = 0.f;
#pragma unroll
    for (int o = 0; o < 16; ++o) ss += acc[o] * acc[o];
    svl[og * 64 + pos] = ss;
    __syncthreads();
    float ssv = 0.f;
#pragma unroll
    for (int g = 1; g < 9; ++g) ssv += svl[g * 64 + pos];
    float vsc = 1.0f / sqrtf(ssv + EPSf);

    if (og == 0) {
        float qsc = 1.0f / sqrtf(ss + EPSf);
#pragma unroll
        for (int o = 0; o < DK; ++o)
            qn[((size_t)b * DK + o) * S + p] = acc[o] * qsc;
    } else {
        int t  = p / (HH * WW);
        int hw = p - t * (HH * WW);
        int h  = hw / WW;
        int w  = hw - h * WW;
        float* vd = vcl
            + (((size_t)(b * VPT + t + 1) * VPH + (h + 3)) * VPW + (w + 3)) * 128
            + (og - 1) * 16;
#pragma unroll
        for (int j = 0; j < 16; j += 4) {
            float4 v4 = {acc[j] * vsc, acc[j + 1] * vsc,
                         acc[j + 2] * vsc, acc[j + 3] * vsc};
            *reinterpret_cast<float4*>(vd + j) = v4;
        }
    }
}

// ---------------------------------------------------------------------------
// k_out: block = (b,t,h) row, 256 threads = 4 waves. (unchanged from R4)
// ---------------------------------------------------------------------------
__global__ __launch_bounds__(256) void k_out(
    const float* __restrict__ vcl, const float* __restrict__ qn,
    const float* __restrict__ wh2, float* __restrict__ out)
{
    __shared__ float q_s[DK * WW];       // 3.5 KB
    __shared__ float weff[WW * WSTR];    // 33.4 KB

    int tid = threadIdx.x;
    // XCD-chunked swizzle: 896 = 8 * 112
    int bid = blockIdx.x;
    int nid = (bid & 7) * 112 + (bid >> 3);
    int b   = nid / 448;
    int rem = nid - b * 448;
    int t   = rem / 56, h = rem - t * 56;
    int pbase = t * (HH * WW) + h * WW;

    for (int i = tid; i < DK * WW; i += 256) {
        int k = i / 56, w = i - k * 56;
        q_s[i] = qn[((size_t)b * DK + k) * S + pbase + w];
    }
    __syncthreads();

    if (tid < 224) {
        int w = tid % 56, q4 = tid / 56;
        float qr[DK];
#pragma unroll
        for (int k = 0; k < DK; ++k) qr[k] = q_s[k * 56 + w];
#pragma unroll 1
        for (int tap = q4; tap < TAPS; tap += 4) {
            float a = 0.f;
#pragma unroll
            for (int k = 0; k < DK; ++k)
                a = fmaf(qr[k], wh2[k * TAPS + tap], a);
            weff[w * WSTR + tap] = a;
        }
    }
    __syncthreads();

    int cc = tid & 31;       // 32 chunks x 4 channels = 128
    int wt = tid >> 5;       // 8 tiles x 7 outputs    = 56
    int wbase = wt * 7;

    const float* vbase = vcl
        + ((size_t)(b * VPT + t) * VPH + h) * VPW * 128
        + (size_t)wbase * 128 + cc * 4;

    float acc[7][4];
#pragma unroll
    for (int k = 0; k < 7; ++k)
#pragma unroll
        for (int j = 0; j < 4; ++j) acc[k][j] = 0.f;

#pragma unroll 1
    for (int dz = 0; dz < 3; ++dz) {
#pragma unroll 1
        for (int dy = 0; dy < 7; ++dy) {
            const float* vr = vbase + (size_t)((dz * VPH + dy) * VPW) * 128;
            const float* wrow = &weff[wbase * WSTR + (dz * 7 + dy) * 7];
#pragma unroll
            for (int j = 0; j < 13; ++j) {
                float4 A = *reinterpret_cast<const float4*>(vr + j * 128);
                int k0 = (j - 6 > 0) ? (j - 6) : 0;
                int k1 = (j < 6) ? j : 6;
#pragma unroll
                for (int k = 0; k < 7; ++k) {
                    if (k < k0 || k > k1) continue;      // compile-time pruned
                    float wv = wrow[k * WSTR + (j - k)];
                    acc[k][0] = fmaf(wv, A.x, acc[k][0]);
                    acc[k][1] = fmaf(wv, A.y, acc[k][1]);
                    acc[k][2] = fmaf(wv, A.z, acc[k][2]);
                    acc[k][3] = fmaf(wv, A.w, acc[k][3]);
                }
            }
        }
    }

    size_t ob = ((size_t)b * DV + cc * 4) * S + pbase + wbase;
#pragma unroll
    for (int j = 0; j < 4; ++j)
#pragma unroll
        for (int k = 0; k < 7; ++k)
            out[ob + (size_t)j * S + k] = acc[k][j];
}

// ---------------------------------------------------------------------------
extern "C" void kernel_launch(void* const* d_in, const int* in_sizes, int n_in,
                              void* d_out, int out_size, void* d_ws, size_t ws_size,
                              hipStream_t stream)
{
    const float* x   = (const float*)d_in[0];   // (2,128,8,56,56)
    const float* Wp  = (const float*)d_in[1];   // (144,128)
    const float* wh2 = (const float*)d_in[2];   // (16,1,3,7,7) -> [k][147]
    float* out = (float*)d_out;                 // (2,128,8,56,56)

    float* ws  = (float*)d_ws;
    float* Wpt = ws;                                   //      18,432 floats
    float* qn  = Wpt + (size_t)CIN * NOUT;             //     802,816 floats
    float* vcl = qn  + (size_t)NB * DK * S;            //   9,840,640 floats

    k_twp <<<dim3((CIN * NOUT + 255) / 256), dim3(256), 0, stream>>>(Wp, Wpt);
    k_zero<<<dim3((PCELLS * 32 + 255) / 256), dim3(256), 0, stream>>>(vcl);
    k_proj<<<dim3(NB * S / 64), dim3(576), 0, stream>>>(x, Wpt, qn, vcl);
    k_out <<<dim3(NB * TT * HH), dim3(256), 0, stream>>>(vcl, qn, wh2, out);
}